// Round 1
// baseline (213.006 us; speedup 1.0000x reference)
//
#include <hip/hip_runtime.h>

// Tucker: res[i][j][k] = sum_{a,b,c} core[a][b][c] * f0[i][a] * f1[j][b] * f2[k][c]
// table = res.reshape(30720, 768); out[n] = table[ids[n]]
// Pipeline:
//   K1: A1[i][b][c] = sum_a f0[i][a] * core[a][b][c]        (40,256,256)
//   K2: A2[i][j][c] = sum_b f1[j][b] * A1[i][b][c]          (40,768,256)
//   K3: out[n][k]   = sum_c A2[ids[n]][c] * f2[k][c]        (8192,768)
// A2 flat row index == i*768+j == table row index, so ids gathers A2 rows directly.

#define A_DIM 40
#define BC 65536   // 256*256
#define C_DIM 256
#define HID 768

// ---------------- K1: mode-0 product (small GEMM, memory-ish) ----------------
__global__ __launch_bounds__(256) void k1_mode0(const float* __restrict__ core,
                                                const float* __restrict__ f0,
                                                float* __restrict__ A1) {
    __shared__ float f0s[A_DIM * A_DIM];
    for (int e = threadIdx.x; e < A_DIM * A_DIM; e += 256) f0s[e] = f0[e];
    __syncthreads();
    const int bc = blockIdx.x * 256 + threadIdx.x;  // [0, 65536)
    float acc[A_DIM];
#pragma unroll
    for (int i = 0; i < A_DIM; ++i) acc[i] = 0.f;
    for (int a = 0; a < A_DIM; ++a) {
        const float cv = core[a * BC + bc];
#pragma unroll
        for (int i = 0; i < A_DIM; ++i) acc[i] += f0s[i * A_DIM + a] * cv;
    }
#pragma unroll
    for (int i = 0; i < A_DIM; ++i) A1[i * BC + bc] = acc[i];
}

// ---------------- K2: batched 768x256x256 GEMM, 64x64 tile, 4x4/thread ------
__global__ __launch_bounds__(256) void k2_gemm(const float* __restrict__ f1,
                                               const float* __restrict__ A1,
                                               float* __restrict__ A2) {
    const int i  = blockIdx.z;
    const int j0 = blockIdx.x * 64;
    const int c0 = blockIdx.y * 64;
    const float* __restrict__ A1i = A1 + i * BC;
    float* __restrict__ A2i = A2 + i * (HID * C_DIM);

    __shared__ float As[16][68];  // [b][j]  (transposed so j is contiguous)
    __shared__ float Bs[16][68];  // [b][c]

    const int tid = threadIdx.x;
    const int tx = tid & 15, ty = tid >> 4;
    float acc[4][4] = {};

    for (int b0 = 0; b0 < C_DIM; b0 += 16) {
#pragma unroll
        for (int r = 0; r < 4; ++r) {
            const int e = tid + 256 * r;
            const int row = e >> 4, col = e & 15;           // row=j-off, col=b-off
            As[col][row] = f1[(j0 + row) * C_DIM + b0 + col];
        }
#pragma unroll
        for (int r = 0; r < 4; ++r) {
            const int e = tid + 256 * r;
            const int row = e >> 6, col = e & 63;           // row=b-off, col=c-off
            Bs[row][col] = A1i[(b0 + row) * C_DIM + c0 + col];
        }
        __syncthreads();
#pragma unroll
        for (int kk = 0; kk < 16; ++kk) {
            const float4 av = *(const float4*)&As[kk][ty * 4];
            const float4 bv = *(const float4*)&Bs[kk][tx * 4];
            const float a4[4] = {av.x, av.y, av.z, av.w};
            const float b4[4] = {bv.x, bv.y, bv.z, bv.w};
#pragma unroll
            for (int p = 0; p < 4; ++p)
#pragma unroll
                for (int q = 0; q < 4; ++q) acc[p][q] += a4[p] * b4[q];
        }
        __syncthreads();
    }
#pragma unroll
    for (int p = 0; p < 4; ++p)
#pragma unroll
        for (int q = 0; q < 4; ++q)
            A2i[(j0 + ty * 4 + p) * C_DIM + c0 + tx * 4 + q] = acc[p][q];
}

// ---------------- K3: gathered GEMM out = G(8192x256) @ f2^T(256x768) -------
__global__ __launch_bounds__(256) void k3_gather_gemm(const float* __restrict__ A2,
                                                      const float* __restrict__ f2,
                                                      const int* __restrict__ ids,
                                                      float* __restrict__ out) {
    const int n0 = blockIdx.x * 64;
    const int k0 = blockIdx.y * 64;

    __shared__ int ids_s[64];
    __shared__ float Gs[16][68];  // [c][n]
    __shared__ float Fs[16][68];  // [c][k]

    const int tid = threadIdx.x;
    if (tid < 64) ids_s[tid] = ids[n0 + tid];
    __syncthreads();

    const int tx = tid & 15, ty = tid >> 4;
    float acc[4][4] = {};

    for (int c0 = 0; c0 < C_DIM; c0 += 16) {
#pragma unroll
        for (int r = 0; r < 4; ++r) {
            const int e = tid + 256 * r;
            const int row = e >> 4, col = e & 15;           // row=n/k-off, col=c-off
            Gs[col][row] = A2[ids_s[row] * C_DIM + c0 + col];
            Fs[col][row] = f2[(k0 + row) * C_DIM + c0 + col];
        }
        __syncthreads();
#pragma unroll
        for (int cc = 0; cc < 16; ++cc) {
            const float4 gv = *(const float4*)&Gs[cc][ty * 4];
            const float4 fv = *(const float4*)&Fs[cc][tx * 4];
            const float g4[4] = {gv.x, gv.y, gv.z, gv.w};
            const float f4[4] = {fv.x, fv.y, fv.z, fv.w};
#pragma unroll
            for (int p = 0; p < 4; ++p)
#pragma unroll
                for (int q = 0; q < 4; ++q) acc[p][q] += g4[p] * f4[q];
        }
        __syncthreads();
    }
#pragma unroll
    for (int p = 0; p < 4; ++p)
#pragma unroll
        for (int q = 0; q < 4; ++q)
            out[(n0 + ty * 4 + p) * HID + k0 + tx * 4 + q] = acc[p][q];
}

extern "C" void kernel_launch(void* const* d_in, const int* in_sizes, int n_in,
                              void* d_out, int out_size, void* d_ws, size_t ws_size,
                              hipStream_t stream) {
    // inputs: 0=x(unused), 1=ids, 2=core, 3=f0, 4=f1, 5=f2
    const int*   ids  = (const int*)d_in[1];
    const float* core = (const float*)d_in[2];
    const float* f0   = (const float*)d_in[3];
    const float* f1   = (const float*)d_in[4];
    const float* f2   = (const float*)d_in[5];
    float* out = (float*)d_out;

    float* A1 = (float*)d_ws;            // 40*65536      = 2,621,440 floats (10.5 MB)
    float* A2 = A1 + A_DIM * BC;         // 40*768*256    = 7,864,320 floats (31.5 MB)

    k1_mode0<<<256, 256, 0, stream>>>(core, f0, A1);
    k2_gemm<<<dim3(12, 4, 40), 256, 0, stream>>>(f1, A1, A2);
    k3_gather_gemm<<<dim3(128, 12), 256, 0, stream>>>(A2, f2, ids, out);
}

// Round 2
// 129.890 us; speedup vs baseline: 1.6399x; 1.6399x over previous
//
#include <hip/hip_runtime.h>

// Tucker reconstruction + gather, bf16 MFMA pipeline:
//   K0 : f1,f2 (f32) -> f1b,f2b (bf16)
//   K1 : A1[i][b][c] = sum_a f0[i][a]*core[a][b][c]   (f32 VALU, bf16 out)
//   K1t: A1t[i][c][b] = transpose(A1[i])              (so B-operand is [n][k-contig])
//   K2 : A2[(i*768+j)][c] = sum_b f1[j][b]*A1t[i][c][b]   (MFMA bf16)
//   K3 : out[n][k] = sum_c A2[ids[n]][c]*f2[k][c]         (MFMA bf16, gathered A)
// table row index == i*768+j == A2 row, ids < 30522 <= 30720 so gather is in-range.

#define A_DIM 40
#define BC 65536   // 256*256
#define C_DIM 256
#define HID 768

typedef __attribute__((ext_vector_type(8))) short short8;   // 8 x bf16 (4 VGPR)
typedef __attribute__((ext_vector_type(4))) float floatx4;  // MFMA C/D

__device__ __forceinline__ unsigned short f2bf(float f) {
    unsigned int u = __builtin_bit_cast(unsigned int, f);
    u += 0x7FFFu + ((u >> 16) & 1u);   // round-to-nearest-even
    return (unsigned short)(u >> 16);
}

// ---------------- K0: f32 -> bf16 convert for f1 and f2 ---------------------
__global__ __launch_bounds__(256) void k0_cvt(const float* __restrict__ f1,
                                              const float* __restrict__ f2,
                                              unsigned short* __restrict__ f1b,
                                              unsigned short* __restrict__ f2b) {
    const int idx = blockIdx.x * 256 + threadIdx.x;       // 0..98303, 49152 float4 per matrix
    const float* src;
    unsigned short* dst;
    int off;
    if (idx < 49152) { src = f1; dst = f1b; off = idx; }
    else             { src = f2; dst = f2b; off = idx - 49152; }
    const float4 v = *(const float4*)&src[off * 4];
    const unsigned int lo = (unsigned int)f2bf(v.x) | ((unsigned int)f2bf(v.y) << 16);
    const unsigned int hi = (unsigned int)f2bf(v.z) | ((unsigned int)f2bf(v.w) << 16);
    *(uint2*)&dst[off * 4] = make_uint2(lo, hi);
}

// ---------------- K1: mode-0 product, f32 compute, bf16 out -----------------
__global__ __launch_bounds__(256) void k1_mode0(const float* __restrict__ core,
                                                const float* __restrict__ f0,
                                                unsigned short* __restrict__ A1) {
    __shared__ float f0s[A_DIM * A_DIM];
    for (int e = threadIdx.x; e < A_DIM * A_DIM; e += 256) f0s[e] = f0[e];
    __syncthreads();
    const int bc = blockIdx.x * 256 + threadIdx.x;
    float acc[A_DIM];
#pragma unroll
    for (int i = 0; i < A_DIM; ++i) acc[i] = 0.f;
    for (int a = 0; a < A_DIM; ++a) {
        const float cv = core[a * BC + bc];
#pragma unroll
        for (int i = 0; i < A_DIM; ++i) acc[i] += f0s[i * A_DIM + a] * cv;
    }
#pragma unroll
    for (int i = 0; i < A_DIM; ++i) A1[i * BC + bc] = f2bf(acc[i]);
}

// ---------------- K1t: per-i 256x256 bf16 transpose (64x64 tiles) -----------
// LDS pitch 66 ushort: bank = (row + col/2) mod 32 on column access -> 2-way (free).
__global__ __launch_bounds__(256) void k1_transpose(const unsigned short* __restrict__ A1,
                                                    unsigned short* __restrict__ A1t) {
    const int i  = blockIdx.z;
    const int b0 = blockIdx.x * 64;
    const int c0 = blockIdx.y * 64;
    const unsigned short* __restrict__ src = A1 + i * BC;
    unsigned short* __restrict__ dst = A1t + i * BC;
    __shared__ unsigned short tile[64 * 66];
    const int t = threadIdx.x;
#pragma unroll
    for (int h = 0; h < 2; ++h) {
        const int s = t + h * 256;
        const int r = s >> 3, cs = (s & 7) * 8;
        short8 v = *(const short8*)&src[(b0 + r) * 256 + c0 + cs];
#pragma unroll
        for (int u = 0; u < 8; ++u) tile[r * 66 + cs + u] = ((unsigned short*)&v)[u];
    }
    __syncthreads();
#pragma unroll
    for (int h = 0; h < 2; ++h) {
        const int s = t + h * 256;
        const int c = s >> 3, bs = (s & 7) * 8;
        short8 o;
#pragma unroll
        for (int u = 0; u < 8; ++u) ((unsigned short*)&o)[u] = tile[(bs + u) * 66 + c];
        *(short8*)&dst[(c0 + c) * 256 + b0 + bs] = o;
    }
}

// ---------------- K2: batched MFMA GEMM, 128x128 tile, BK=32 ----------------
// A = f1b [j][b] (M=768,K=256), B^T = A1t[i] [c][b] (N=256,K=256), C = A2 bf16
#define LP 40  // LDS row pitch in ushort (80 B = 20 banks; frag reads 2-way max)
__global__ __launch_bounds__(256) void k2_gemm(const unsigned short* __restrict__ f1b,
                                               const unsigned short* __restrict__ A1t,
                                               unsigned short* __restrict__ A2) {
    const int i  = blockIdx.z;
    const int j0 = blockIdx.x * 128;
    const int c0 = blockIdx.y * 128;
    const unsigned short* __restrict__ Bsrc = A1t + i * BC;

    __shared__ unsigned short As[128 * LP];
    __shared__ unsigned short Bs[128 * LP];

    const int tid = threadIdx.x;
    const int lane = tid & 63, wave = tid >> 6;
    const int wm = (wave >> 1) * 64, wn = (wave & 1) * 64;
    const int l16 = lane & 15, q = lane >> 4;
    const int r0 = tid >> 2, seg0 = (tid & 3) * 8;   // staging: rows r0 and r0+64

    floatx4 acc[4][4];
#pragma unroll
    for (int p = 0; p < 4; ++p)
#pragma unroll
        for (int r = 0; r < 4; ++r) acc[p][r] = (floatx4)0.f;

    for (int kk = 0; kk < C_DIM; kk += 32) {
        const short8 a0 = *(const short8*)&f1b[(j0 + r0) * 256 + kk + seg0];
        const short8 a1 = *(const short8*)&f1b[(j0 + 64 + r0) * 256 + kk + seg0];
        const short8 b0 = *(const short8*)&Bsrc[(c0 + r0) * 256 + kk + seg0];
        const short8 b1 = *(const short8*)&Bsrc[(c0 + 64 + r0) * 256 + kk + seg0];
        *(short8*)&As[r0 * LP + seg0] = a0;
        *(short8*)&As[(r0 + 64) * LP + seg0] = a1;
        *(short8*)&Bs[r0 * LP + seg0] = b0;
        *(short8*)&Bs[(r0 + 64) * LP + seg0] = b1;
        __syncthreads();
        short8 af[4], bf[4];
#pragma unroll
        for (int p = 0; p < 4; ++p) af[p] = *(const short8*)&As[(wm + p * 16 + l16) * LP + q * 8];
#pragma unroll
        for (int r = 0; r < 4; ++r) bf[r] = *(const short8*)&Bs[(wn + r * 16 + l16) * LP + q * 8];
#pragma unroll
        for (int p = 0; p < 4; ++p)
#pragma unroll
            for (int r = 0; r < 4; ++r)
                acc[p][r] = __builtin_amdgcn_mfma_f32_16x16x32_bf16(af[p], bf[r], acc[p][r], 0, 0, 0);
        __syncthreads();
    }
    unsigned short* __restrict__ Cout = A2 + (size_t)i * HID * C_DIM;
#pragma unroll
    for (int p = 0; p < 4; ++p)
#pragma unroll
        for (int r = 0; r < 4; ++r)
#pragma unroll
            for (int rr = 0; rr < 4; ++rr) {
                const int row = j0 + wm + p * 16 + q * 4 + rr;   // C: row=(lane>>4)*4+reg
                const int col = c0 + wn + r * 16 + l16;          //    col=lane&15
                Cout[row * 256 + col] = f2bf(acc[p][r][rr]);
            }
}

// ---------------- K3: gathered MFMA GEMM, out f32 ---------------------------
// A = gathered A2 rows [n][c] (M=8192,K=256), B^T = f2b [k][c] (N=768)
__global__ __launch_bounds__(256) void k3_gemm(const unsigned short* __restrict__ A2,
                                               const unsigned short* __restrict__ f2b,
                                               const int* __restrict__ ids,
                                               float* __restrict__ out) {
    const int n0 = blockIdx.x * 128;
    const int k0 = blockIdx.y * 128;

    __shared__ int ids_s[128];
    __shared__ unsigned short As[128 * LP];
    __shared__ unsigned short Bs[128 * LP];

    const int tid = threadIdx.x;
    if (tid < 128) ids_s[tid] = ids[n0 + tid];
    __syncthreads();

    const int lane = tid & 63, wave = tid >> 6;
    const int wm = (wave >> 1) * 64, wn = (wave & 1) * 64;
    const int l16 = lane & 15, q = lane >> 4;
    const int r0 = tid >> 2, seg0 = (tid & 3) * 8;
    const int ga = ids_s[r0];
    const int gb = ids_s[64 + r0];

    floatx4 acc[4][4];
#pragma unroll
    for (int p = 0; p < 4; ++p)
#pragma unroll
        for (int r = 0; r < 4; ++r) acc[p][r] = (floatx4)0.f;

    for (int kk = 0; kk < C_DIM; kk += 32) {
        const short8 a0 = *(const short8*)&A2[(size_t)ga * 256 + kk + seg0];
        const short8 a1 = *(const short8*)&A2[(size_t)gb * 256 + kk + seg0];
        const short8 b0 = *(const short8*)&f2b[(k0 + r0) * 256 + kk + seg0];
        const short8 b1 = *(const short8*)&f2b[(k0 + 64 + r0) * 256 + kk + seg0];
        *(short8*)&As[r0 * LP + seg0] = a0;
        *(short8*)&As[(r0 + 64) * LP + seg0] = a1;
        *(short8*)&Bs[r0 * LP + seg0] = b0;
        *(short8*)&Bs[(r0 + 64) * LP + seg0] = b1;
        __syncthreads();
        short8 af[4], bf[4];
#pragma unroll
        for (int p = 0; p < 4; ++p) af[p] = *(const short8*)&As[(wm + p * 16 + l16) * LP + q * 8];
#pragma unroll
        for (int r = 0; r < 4; ++r) bf[r] = *(const short8*)&Bs[(wn + r * 16 + l16) * LP + q * 8];
#pragma unroll
        for (int p = 0; p < 4; ++p)
#pragma unroll
            for (int r = 0; r < 4; ++r)
                acc[p][r] = __builtin_amdgcn_mfma_f32_16x16x32_bf16(af[p], bf[r], acc[p][r], 0, 0, 0);
        __syncthreads();
    }
#pragma unroll
    for (int p = 0; p < 4; ++p)
#pragma unroll
        for (int r = 0; r < 4; ++r)
#pragma unroll
            for (int rr = 0; rr < 4; ++rr) {
                const int row = n0 + wm + p * 16 + q * 4 + rr;
                const int col = k0 + wn + r * 16 + l16;
                out[(size_t)row * HID + col] = acc[p][r][rr];
            }
}

extern "C" void kernel_launch(void* const* d_in, const int* in_sizes, int n_in,
                              void* d_out, int out_size, void* d_ws, size_t ws_size,
                              hipStream_t stream) {
    // inputs: 0=x(unused), 1=ids, 2=core, 3=f0, 4=f1, 5=f2
    const int*   ids  = (const int*)d_in[1];
    const float* core = (const float*)d_in[2];
    const float* f0   = (const float*)d_in[3];
    const float* f1   = (const float*)d_in[4];
    const float* f2   = (const float*)d_in[5];
    float* out = (float*)d_out;

    char* ws = (char*)d_ws;
    unsigned short* A1  = (unsigned short*)ws;                 //  5,242,880 B
    unsigned short* A1t = (unsigned short*)(ws + 5242880);     //  5,242,880 B
    unsigned short* A2  = (unsigned short*)(ws + 10485760);    // 15,728,640 B
    unsigned short* f1b = (unsigned short*)(ws + 26214400);    //    393,216 B
    unsigned short* f2b = (unsigned short*)(ws + 26607616);    //    393,216 B

    k0_cvt<<<384, 256, 0, stream>>>(f1, f2, f1b, f2b);
    k1_mode0<<<256, 256, 0, stream>>>(core, f0, A1);
    k1_transpose<<<dim3(4, 4, A_DIM), 256, 0, stream>>>(A1, A1t);
    k2_gemm<<<dim3(6, 2, A_DIM), 256, 0, stream>>>(f1b, A1t, A2);
    k3_gemm<<<dim3(64, 6), 256, 0, stream>>>(A2, f2b, ids, out);
}

// Round 3
// 127.465 us; speedup vs baseline: 1.6711x; 1.0190x over previous
//
#include <hip/hip_runtime.h>

// Tucker reconstruction + gather, bf16 MFMA pipeline:
//   K0 : f1,f2 (f32) -> f1b,f2b (bf16)
//   K1 : A1[i][b][c] = sum_a f0[i][a]*core[a][b][c]   (f32 VALU, bf16 out)
//   K1t: A1t[i][c][b] = transpose(A1[i])              (B-operand wants [n][k-contig])
//   K2 : A2[(i*768+j)][c] = sum_b f1[j][b]*A1t[i][c][b]   (MFMA bf16, global_load_lds)
//   K3 : out[n][k] = sum_c A2[ids[n]][c]*f2[k][c]         (MFMA bf16, gathered A rows)
// table row index == i*768+j == A2 row; ids < 30522 <= 30720 so gather is in-range.

#define A_DIM 40
#define BC 65536   // 256*256
#define C_DIM 256
#define HID 768

typedef __attribute__((ext_vector_type(8))) short short8;   // 8 x bf16 (4 VGPR)
typedef __attribute__((ext_vector_type(4))) float floatx4;  // MFMA C/D

#define AS1 __attribute__((address_space(1)))
#define AS3 __attribute__((address_space(3)))

// async 16B global->LDS DMA: per-lane global addr, wave-uniform LDS base,
// HW writes lane i at base + i*16 (no per-lane LDS scatter).
__device__ __forceinline__ void gl2lds16(const unsigned short* g, unsigned short* l) {
    __builtin_amdgcn_global_load_lds((const AS1 unsigned int*)g, (AS3 unsigned int*)l,
                                     16, 0, 0);
}

__device__ __forceinline__ unsigned short f2bf(float f) {
    unsigned int u = __builtin_bit_cast(unsigned int, f);
    u += 0x7FFFu + ((u >> 16) & 1u);   // round-to-nearest-even
    return (unsigned short)(u >> 16);
}

// ---------------- K0: f32 -> bf16 convert for f1 and f2 ---------------------
__global__ __launch_bounds__(256) void k0_cvt(const float* __restrict__ f1,
                                              const float* __restrict__ f2,
                                              unsigned short* __restrict__ f1b,
                                              unsigned short* __restrict__ f2b) {
    const int idx = blockIdx.x * 256 + threadIdx.x;       // 49152 float4 per matrix
    const float* src;
    unsigned short* dst;
    int off;
    if (idx < 49152) { src = f1; dst = f1b; off = idx; }
    else             { src = f2; dst = f2b; off = idx - 49152; }
    const float4 v = *(const float4*)&src[off * 4];
    const unsigned int lo = (unsigned int)f2bf(v.x) | ((unsigned int)f2bf(v.y) << 16);
    const unsigned int hi = (unsigned int)f2bf(v.z) | ((unsigned int)f2bf(v.w) << 16);
    *(uint2*)&dst[off * 4] = make_uint2(lo, hi);
}

// ---------------- K1: mode-0 product, f32 compute, bf16 out -----------------
__global__ __launch_bounds__(256) void k1_mode0(const float* __restrict__ core,
                                                const float* __restrict__ f0,
                                                unsigned short* __restrict__ A1) {
    __shared__ float f0s[A_DIM * A_DIM];
    for (int e = threadIdx.x; e < A_DIM * A_DIM; e += 256) f0s[e] = f0[e];
    __syncthreads();
    const int bc = blockIdx.x * 256 + threadIdx.x;
    float acc[A_DIM];
#pragma unroll
    for (int i = 0; i < A_DIM; ++i) acc[i] = 0.f;
    for (int a = 0; a < A_DIM; ++a) {
        const float cv = core[a * BC + bc];
#pragma unroll
        for (int i = 0; i < A_DIM; ++i) acc[i] += f0s[i * A_DIM + a] * cv;
    }
#pragma unroll
    for (int i = 0; i < A_DIM; ++i) A1[i * BC + bc] = f2bf(acc[i]);
}

// ---------------- K1t: per-i 256x256 bf16 transpose (64x64 tiles) -----------
__global__ __launch_bounds__(256) void k1_transpose(const unsigned short* __restrict__ A1,
                                                    unsigned short* __restrict__ A1t) {
    const int i  = blockIdx.z;
    const int b0 = blockIdx.x * 64;
    const int c0 = blockIdx.y * 64;
    const unsigned short* __restrict__ src = A1 + i * BC;
    unsigned short* __restrict__ dst = A1t + i * BC;
    __shared__ unsigned short tile[64 * 66];
    const int t = threadIdx.x;
#pragma unroll
    for (int h = 0; h < 2; ++h) {
        const int s = t + h * 256;
        const int r = s >> 3, cs = (s & 7) * 8;
        short8 v = *(const short8*)&src[(b0 + r) * 256 + c0 + cs];
#pragma unroll
        for (int u = 0; u < 8; ++u) tile[r * 66 + cs + u] = ((unsigned short*)&v)[u];
    }
    __syncthreads();
#pragma unroll
    for (int h = 0; h < 2; ++h) {
        const int s = t + h * 256;
        const int c = s >> 3, bs = (s & 7) * 8;
        short8 o;
#pragma unroll
        for (int u = 0; u < 8; ++u) ((unsigned short*)&o)[u] = tile[(bs + u) * 66 + c];
        *(short8*)&dst[(c0 + c) * 256 + b0 + bs] = o;
    }
}

// ---------------- K2: batched MFMA GEMM, 128x128 tile, BK=32, DMA staging ---
// A = f1b [j][b] (M=768,K=256), B^T = A1t[i] [c][b] (N=256,K=256), C = A2 bf16
// LDS tiles packed [row][32] (64B/row, 4 chunks of 16B); chunk c -> row c>>2.
__global__ __launch_bounds__(256) void k2_gemm(const unsigned short* __restrict__ f1b,
                                               const unsigned short* __restrict__ A1t,
                                               unsigned short* __restrict__ A2) {
    const int i  = blockIdx.z;
    const int j0 = blockIdx.x * 128;
    const int c0 = blockIdx.y * 128;
    const unsigned short* __restrict__ Bsrc = A1t + i * BC;

    __shared__ unsigned short As[128 * 32];
    __shared__ unsigned short Bs[128 * 32];

    const int tid = threadIdx.x;
    const int lane = tid & 63, wave = tid >> 6;
    const int wm = (wave >> 1) * 64, wn = (wave & 1) * 64;
    const int l16 = lane & 15, q = lane >> 4;

    // staging chunks: issue0 handles chunk tid, issue1 chunk tid+256
    const int r_lo = tid >> 2,         o_lo = (tid & 3) * 8;
    const int r_hi = (tid + 256) >> 2, o_hi = (tid & 3) * 8;
    unsigned short* AsW0 = &As[wave * 512];           // chunks wave*64 .. +63
    unsigned short* AsW1 = &As[2048 + wave * 512];
    unsigned short* BsW0 = &Bs[wave * 512];
    unsigned short* BsW1 = &Bs[2048 + wave * 512];

    floatx4 acc[4][4];
#pragma unroll
    for (int p = 0; p < 4; ++p)
#pragma unroll
        for (int r = 0; r < 4; ++r) acc[p][r] = (floatx4)0.f;

    for (int kk = 0; kk < C_DIM; kk += 32) {
        gl2lds16(&f1b[(j0 + r_lo) * 256 + kk + o_lo], AsW0);
        gl2lds16(&f1b[(j0 + r_hi) * 256 + kk + o_hi], AsW1);
        gl2lds16(&Bsrc[(c0 + r_lo) * 256 + kk + o_lo], BsW0);
        gl2lds16(&Bsrc[(c0 + r_hi) * 256 + kk + o_hi], BsW1);
        __syncthreads();
        short8 af[4], bf[4];
#pragma unroll
        for (int p = 0; p < 4; ++p) af[p] = *(const short8*)&As[(wm + p * 16 + l16) * 32 + q * 8];
#pragma unroll
        for (int r = 0; r < 4; ++r) bf[r] = *(const short8*)&Bs[(wn + r * 16 + l16) * 32 + q * 8];
#pragma unroll
        for (int p = 0; p < 4; ++p)
#pragma unroll
            for (int r = 0; r < 4; ++r)
                acc[p][r] = __builtin_amdgcn_mfma_f32_16x16x32_bf16(af[p], bf[r], acc[p][r], 0, 0, 0);
        __syncthreads();
    }
    unsigned short* __restrict__ Cout = A2 + (size_t)i * HID * C_DIM;
#pragma unroll
    for (int p = 0; p < 4; ++p)
#pragma unroll
        for (int r = 0; r < 4; ++r)
#pragma unroll
            for (int rr = 0; rr < 4; ++rr) {
                const int row = j0 + wm + p * 16 + q * 4 + rr;   // C: row=(lane>>4)*4+reg
                const int col = c0 + wn + r * 16 + l16;          //    col=lane&15
                Cout[row * 256 + col] = f2bf(acc[p][r][rr]);
            }
}

// ---------------- K3: gathered MFMA GEMM, DMA staging, out f32 --------------
// A = gathered A2 rows [n][c] (M=8192,K=256), B^T = f2b [k][c] (N=768)
__global__ __launch_bounds__(256) void k3_gemm(const unsigned short* __restrict__ A2,
                                               const unsigned short* __restrict__ f2b,
                                               const int* __restrict__ ids,
                                               float* __restrict__ out) {
    const int n0 = blockIdx.x * 128;
    const int k0 = blockIdx.y * 128;

    __shared__ int ids_s[128];
    __shared__ unsigned short As[128 * 32];
    __shared__ unsigned short Bs[128 * 32];

    const int tid = threadIdx.x;
    if (tid < 128) ids_s[tid] = ids[n0 + tid];
    __syncthreads();

    const int lane = tid & 63, wave = tid >> 6;
    const int wm = (wave >> 1) * 64, wn = (wave & 1) * 64;
    const int l16 = lane & 15, q = lane >> 4;

    const int r_lo = tid >> 2,         o_lo = (tid & 3) * 8;
    const int r_hi = (tid + 256) >> 2, o_hi = (tid & 3) * 8;
    const size_t ga = (size_t)ids_s[r_lo] * 256;   // gathered A rows
    const size_t gb = (size_t)ids_s[r_hi] * 256;
    unsigned short* AsW0 = &As[wave * 512];
    unsigned short* AsW1 = &As[2048 + wave * 512];
    unsigned short* BsW0 = &Bs[wave * 512];
    unsigned short* BsW1 = &Bs[2048 + wave * 512];

    floatx4 acc[4][4];
#pragma unroll
    for (int p = 0; p < 4; ++p)
#pragma unroll
        for (int r = 0; r < 4; ++r) acc[p][r] = (floatx4)0.f;

    for (int kk = 0; kk < C_DIM; kk += 32) {
        gl2lds16(&A2[ga + kk + o_lo], AsW0);
        gl2lds16(&A2[gb + kk + o_hi], AsW1);
        gl2lds16(&f2b[(k0 + r_lo) * 256 + kk + o_lo], BsW0);
        gl2lds16(&f2b[(k0 + r_hi) * 256 + kk + o_hi], BsW1);
        __syncthreads();
        short8 af[4], bf[4];
#pragma unroll
        for (int p = 0; p < 4; ++p) af[p] = *(const short8*)&As[(wm + p * 16 + l16) * 32 + q * 8];
#pragma unroll
        for (int r = 0; r < 4; ++r) bf[r] = *(const short8*)&Bs[(wn + r * 16 + l16) * 32 + q * 8];
#pragma unroll
        for (int p = 0; p < 4; ++p)
#pragma unroll
            for (int r = 0; r < 4; ++r)
                acc[p][r] = __builtin_amdgcn_mfma_f32_16x16x32_bf16(af[p], bf[r], acc[p][r], 0, 0, 0);
        __syncthreads();
    }
#pragma unroll
    for (int p = 0; p < 4; ++p)
#pragma unroll
        for (int r = 0; r < 4; ++r)
#pragma unroll
            for (int rr = 0; rr < 4; ++rr) {
                const int row = n0 + wm + p * 16 + q * 4 + rr;
                const int col = k0 + wn + r * 16 + l16;
                out[(size_t)row * HID + col] = acc[p][r][rr];
            }
}

extern "C" void kernel_launch(void* const* d_in, const int* in_sizes, int n_in,
                              void* d_out, int out_size, void* d_ws, size_t ws_size,
                              hipStream_t stream) {
    // inputs: 0=x(unused), 1=ids, 2=core, 3=f0, 4=f1, 5=f2
    const int*   ids  = (const int*)d_in[1];
    const float* core = (const float*)d_in[2];
    const float* f0   = (const float*)d_in[3];
    const float* f1   = (const float*)d_in[4];
    const float* f2   = (const float*)d_in[5];
    float* out = (float*)d_out;

    char* ws = (char*)d_ws;
    unsigned short* A1  = (unsigned short*)ws;                 //  5,242,880 B
    unsigned short* A1t = (unsigned short*)(ws + 5242880);     //  5,242,880 B
    unsigned short* A2  = (unsigned short*)(ws + 10485760);    // 15,728,640 B
    unsigned short* f1b = (unsigned short*)(ws + 26214400);    //    393,216 B
    unsigned short* f2b = (unsigned short*)(ws + 26607616);    //    393,216 B

    k0_cvt<<<384, 256, 0, stream>>>(f1, f2, f1b, f2b);
    k1_mode0<<<256, 256, 0, stream>>>(core, f0, A1);
    k1_transpose<<<dim3(4, 4, A_DIM), 256, 0, stream>>>(A1, A1t);
    k2_gemm<<<dim3(6, 2, A_DIM), 256, 0, stream>>>(f1b, A1t, A2);
    k3_gemm<<<dim3(64, 6), 256, 0, stream>>>(A2, f2b, ids, out);
}

// Round 4
// 118.272 us; speedup vs baseline: 1.8010x; 1.0777x over previous
//
#include <hip/hip_runtime.h>

// Tucker reconstruction + gather, bf16 MFMA pipeline:
//   K01: fused  [f1,f2 -> bf16 cvt]  +  [A1[i][b][c] = sum_a f0[i][a]*core[a][b][c]]
//   K1t: A1t[i][c][b] = transpose(A1[i])   (B-operand wants [n][k-contig])
//   K2 : A2[(i*768+j)][c] = sum_b f1[j][b]*A1t[i][c][b]   (MFMA bf16, 64x64 tiles)
//   K3 : out[n][k] = sum_c A2[ids[n]][c]*f2[k][c]         (MFMA bf16, gathered rows)
// table row index == i*768+j == A2 row; ids < 30522 <= 30720 so gather is in-range.
// Round-4 theory: grids were 480/384 blocks on 256 CUs (<2 blocks/CU) -> barrier
// drains unhidden. 64x64 tiles give 1920/1536 blocks (6-7.5/CU) for TLP overlap.

#define A_DIM 40
#define BC 65536   // 256*256
#define C_DIM 256
#define HID 768

typedef __attribute__((ext_vector_type(8))) short short8;   // 8 x bf16 (4 VGPR)
typedef __attribute__((ext_vector_type(4))) float floatx4;  // MFMA C/D

#define AS1 __attribute__((address_space(1)))
#define AS3 __attribute__((address_space(3)))

// async 16B global->LDS DMA: per-lane global addr (gather OK), wave-uniform LDS
// base; HW writes lane i at base + i*16.
__device__ __forceinline__ void gl2lds16(const unsigned short* g, unsigned short* l) {
    __builtin_amdgcn_global_load_lds((const AS1 unsigned int*)g, (AS3 unsigned int*)l,
                                     16, 0, 0);
}

__device__ __forceinline__ unsigned short f2bf(float f) {
    unsigned int u = __builtin_bit_cast(unsigned int, f);
    u += 0x7FFFu + ((u >> 16) & 1u);   // round-to-nearest-even
    return (unsigned short)(u >> 16);
}

// ---------------- K01: fused cvt + mode-0 product ---------------------------
// blocks [0,1024): mode-0, i-split x4 (block b: i in [10*(b>>8), +10), bc = (b&255)*256+tid)
// blocks [1024,1408): f1/f2 -> bf16 convert
__global__ __launch_bounds__(256) void k01_cvt_mode0(const float* __restrict__ core,
                                                     const float* __restrict__ f0,
                                                     const float* __restrict__ f1,
                                                     const float* __restrict__ f2,
                                                     unsigned short* __restrict__ A1,
                                                     unsigned short* __restrict__ f1b,
                                                     unsigned short* __restrict__ f2b) {
    const int bid = blockIdx.x;
    if (bid < 1024) {
        __shared__ float f0s[A_DIM * A_DIM];
        const int i0 = (bid >> 8) * 10;
        for (int e = threadIdx.x; e < A_DIM * A_DIM; e += 256) f0s[e] = f0[e];
        __syncthreads();
        const int bc = (bid & 255) * 256 + threadIdx.x;
        float acc[10];
#pragma unroll
        for (int ii = 0; ii < 10; ++ii) acc[ii] = 0.f;
        for (int a = 0; a < A_DIM; ++a) {
            const float cv = core[a * BC + bc];
#pragma unroll
            for (int ii = 0; ii < 10; ++ii) acc[ii] += f0s[(i0 + ii) * A_DIM + a] * cv;
        }
#pragma unroll
        for (int ii = 0; ii < 10; ++ii) A1[(i0 + ii) * BC + bc] = f2bf(acc[ii]);
    } else {
        const int idx = (bid - 1024) * 256 + threadIdx.x;   // 49152 float4 per matrix
        const float* src;
        unsigned short* dst;
        int off;
        if (idx < 49152) { src = f1; dst = f1b; off = idx; }
        else             { src = f2; dst = f2b; off = idx - 49152; }
        const float4 v = *(const float4*)&src[off * 4];
        const unsigned int lo = (unsigned int)f2bf(v.x) | ((unsigned int)f2bf(v.y) << 16);
        const unsigned int hi = (unsigned int)f2bf(v.z) | ((unsigned int)f2bf(v.w) << 16);
        *(uint2*)&dst[off * 4] = make_uint2(lo, hi);
    }
}

// ---------------- K1t: per-i 256x256 bf16 transpose (64x64 tiles) -----------
__global__ __launch_bounds__(256) void k1_transpose(const unsigned short* __restrict__ A1,
                                                    unsigned short* __restrict__ A1t) {
    const int i  = blockIdx.z;
    const int b0 = blockIdx.x * 64;
    const int c0 = blockIdx.y * 64;
    const unsigned short* __restrict__ src = A1 + i * BC;
    unsigned short* __restrict__ dst = A1t + i * BC;
    __shared__ unsigned short tile[64 * 66];
    const int t = threadIdx.x;
#pragma unroll
    for (int h = 0; h < 2; ++h) {
        const int s = t + h * 256;
        const int r = s >> 3, cs = (s & 7) * 8;
        short8 v = *(const short8*)&src[(b0 + r) * 256 + c0 + cs];
#pragma unroll
        for (int u = 0; u < 8; ++u) tile[r * 66 + cs + u] = ((unsigned short*)&v)[u];
    }
    __syncthreads();
#pragma unroll
    for (int h = 0; h < 2; ++h) {
        const int s = t + h * 256;
        const int c = s >> 3, bs = (s & 7) * 8;
        short8 o;
#pragma unroll
        for (int u = 0; u < 8; ++u) ((unsigned short*)&o)[u] = tile[(bs + u) * 66 + c];
        *(short8*)&dst[(c0 + c) * 256 + b0 + bs] = o;
    }
}

// ---------------- K2: batched MFMA GEMM, 64x64 tile, BK=32, DMA staging -----
// A = f1b [j][b] (M=768,K=256), B^T = A1t[i] [c][b] (N=256,K=256), C = A2 bf16
// LDS tiles packed [row][32] (64B/row); chunk tid -> row tid>>2, 16B slot tid&3.
__global__ __launch_bounds__(256) void k2_gemm(const unsigned short* __restrict__ f1b,
                                               const unsigned short* __restrict__ A1t,
                                               unsigned short* __restrict__ A2) {
    const int i  = blockIdx.z;
    const int j0 = blockIdx.x * 64;
    const int c0 = blockIdx.y * 64;
    const unsigned short* __restrict__ Bsrc = A1t + i * BC;

    __shared__ unsigned short As[64 * 32];
    __shared__ unsigned short Bs[64 * 32];

    const int tid = threadIdx.x;
    const int lane = tid & 63, wave = tid >> 6;
    const int wm = (wave >> 1) * 32, wn = (wave & 1) * 32;
    const int l16 = lane & 15, q = lane >> 4;

    const int r0 = tid >> 2, o0 = (tid & 3) * 8;     // staging chunk -> (row, 16B slot)
    unsigned short* AsW = &As[wave * 512];           // wave covers chunks wave*64..+63
    unsigned short* BsW = &Bs[wave * 512];

    floatx4 acc[2][2];
#pragma unroll
    for (int p = 0; p < 2; ++p)
#pragma unroll
        for (int r = 0; r < 2; ++r) acc[p][r] = (floatx4)0.f;

    for (int kk = 0; kk < C_DIM; kk += 32) {
        gl2lds16(&f1b[(j0 + r0) * 256 + kk + o0], AsW);
        gl2lds16(&Bsrc[(c0 + r0) * 256 + kk + o0], BsW);
        __syncthreads();
        short8 af[2], bf[2];
#pragma unroll
        for (int p = 0; p < 2; ++p) af[p] = *(const short8*)&As[(wm + p * 16 + l16) * 32 + q * 8];
#pragma unroll
        for (int r = 0; r < 2; ++r) bf[r] = *(const short8*)&Bs[(wn + r * 16 + l16) * 32 + q * 8];
#pragma unroll
        for (int p = 0; p < 2; ++p)
#pragma unroll
            for (int r = 0; r < 2; ++r)
                acc[p][r] = __builtin_amdgcn_mfma_f32_16x16x32_bf16(af[p], bf[r], acc[p][r], 0, 0, 0);
        __syncthreads();
    }
    unsigned short* __restrict__ Cout = A2 + (size_t)i * HID * C_DIM;
#pragma unroll
    for (int p = 0; p < 2; ++p)
#pragma unroll
        for (int r = 0; r < 2; ++r)
#pragma unroll
            for (int rr = 0; rr < 4; ++rr) {
                const int row = j0 + wm + p * 16 + q * 4 + rr;   // C: row=(lane>>4)*4+reg
                const int col = c0 + wn + r * 16 + l16;          //    col=lane&15
                Cout[row * 256 + col] = f2bf(acc[p][r][rr]);
            }
}

// ---------------- K3: gathered MFMA GEMM, 64x64 tile, out f32 ---------------
// A = gathered A2 rows [n][c] (M=8192,K=256), B^T = f2b [k][c] (N=768)
__global__ __launch_bounds__(256) void k3_gemm(const unsigned short* __restrict__ A2,
                                               const unsigned short* __restrict__ f2b,
                                               const int* __restrict__ ids,
                                               float* __restrict__ out) {
    const int n0 = blockIdx.x * 64;
    const int k0 = blockIdx.y * 64;

    __shared__ int ids_s[64];
    __shared__ unsigned short As[64 * 32];
    __shared__ unsigned short Bs[64 * 32];

    const int tid = threadIdx.x;
    if (tid < 64) ids_s[tid] = ids[n0 + tid];
    __syncthreads();

    const int lane = tid & 63, wave = tid >> 6;
    const int wm = (wave >> 1) * 32, wn = (wave & 1) * 32;
    const int l16 = lane & 15, q = lane >> 4;

    const int r0 = tid >> 2, o0 = (tid & 3) * 8;
    const size_t ga = (size_t)ids_s[r0] * 256;       // gathered A row base
    unsigned short* AsW = &As[wave * 512];
    unsigned short* BsW = &Bs[wave * 512];

    floatx4 acc[2][2];
#pragma unroll
    for (int p = 0; p < 2; ++p)
#pragma unroll
        for (int r = 0; r < 2; ++r) acc[p][r] = (floatx4)0.f;

    for (int kk = 0; kk < C_DIM; kk += 32) {
        gl2lds16(&A2[ga + kk + o0], AsW);
        gl2lds16(&f2b[(k0 + r0) * 256 + kk + o0], BsW);
        __syncthreads();
        short8 af[2], bf[2];
#pragma unroll
        for (int p = 0; p < 2; ++p) af[p] = *(const short8*)&As[(wm + p * 16 + l16) * 32 + q * 8];
#pragma unroll
        for (int r = 0; r < 2; ++r) bf[r] = *(const short8*)&Bs[(wn + r * 16 + l16) * 32 + q * 8];
#pragma unroll
        for (int p = 0; p < 2; ++p)
#pragma unroll
            for (int r = 0; r < 2; ++r)
                acc[p][r] = __builtin_amdgcn_mfma_f32_16x16x32_bf16(af[p], bf[r], acc[p][r], 0, 0, 0);
        __syncthreads();
    }
#pragma unroll
    for (int p = 0; p < 2; ++p)
#pragma unroll
        for (int r = 0; r < 2; ++r)
#pragma unroll
            for (int rr = 0; rr < 4; ++rr) {
                const int row = n0 + wm + p * 16 + q * 4 + rr;
                const int col = k0 + wn + r * 16 + l16;
                out[(size_t)row * HID + col] = acc[p][r][rr];
            }
}

extern "C" void kernel_launch(void* const* d_in, const int* in_sizes, int n_in,
                              void* d_out, int out_size, void* d_ws, size_t ws_size,
                              hipStream_t stream) {
    // inputs: 0=x(unused), 1=ids, 2=core, 3=f0, 4=f1, 5=f2
    const int*   ids  = (const int*)d_in[1];
    const float* core = (const float*)d_in[2];
    const float* f0   = (const float*)d_in[3];
    const float* f1   = (const float*)d_in[4];
    const float* f2   = (const float*)d_in[5];
    float* out = (float*)d_out;

    char* ws = (char*)d_ws;
    unsigned short* A1  = (unsigned short*)ws;                 //  5,242,880 B
    unsigned short* A1t = (unsigned short*)(ws + 5242880);     //  5,242,880 B
    unsigned short* A2  = (unsigned short*)(ws + 10485760);    // 15,728,640 B
    unsigned short* f1b = (unsigned short*)(ws + 26214400);    //    393,216 B
    unsigned short* f2b = (unsigned short*)(ws + 26607616);    //    393,216 B

    k01_cvt_mode0<<<1408, 256, 0, stream>>>(core, f0, f1, f2, A1, f1b, f2b);
    k1_transpose<<<dim3(4, 4, A_DIM), 256, 0, stream>>>(A1, A1t);
    k2_gemm<<<dim3(12, 4, A_DIM), 256, 0, stream>>>(f1b, A1t, A2);
    k3_gemm<<<dim3(128, 12), 256, 0, stream>>>(A2, f2b, ids, out);
}

// Round 6
// 114.116 us; speedup vs baseline: 1.8666x; 1.0364x over previous
//
#include <hip/hip_runtime.h>

// Tucker reconstruction + gather, bf16 MFMA pipeline (3 dispatches):
//   K01f: [f1,f2 -> bf16 cvt blocks]  +  [fused mode-0 + transpose:
//          A1t[i][c][b] = sum_a f0[i][a]*core[a][b][c], written directly]
//   K2  : A2[(i*768+j)][c] = sum_b f1[j][b]*A1t[i][c][b]   (MFMA bf16, 64x64)
//   K3  : out[n][k] = sum_c A2[ids[n]][c]*f2[k][c]         (MFMA bf16, gathered)
// table row index == i*768+j == A2 row; ids < 30522 <= 30720 so gather is in-range.
// NOTE (round-5 lesson): hipLaunchCooperativeKernel silently fails in this
// harness (out stayed zero) -> plain launches only.

#define A_DIM 40
#define BC 65536   // 256*256
#define C_DIM 256
#define HID 768

typedef __attribute__((ext_vector_type(8))) short short8;   // 8 x bf16 (4 VGPR)
typedef __attribute__((ext_vector_type(4))) float floatx4;  // MFMA C/D

#define AS1 __attribute__((address_space(1)))
#define AS3 __attribute__((address_space(3)))

// async 16B global->LDS DMA: per-lane global addr (gather OK), wave-uniform LDS
// base; HW writes lane i at base + i*16.
__device__ __forceinline__ void gl2lds16(const unsigned short* g, unsigned short* l) {
    __builtin_amdgcn_global_load_lds((const AS1 unsigned int*)g, (AS3 unsigned int*)l,
                                     16, 0, 0);
}

__device__ __forceinline__ unsigned short f2bf(float f) {
    unsigned int u = __builtin_bit_cast(unsigned int, f);
    u += 0x7FFFu + ((u >> 16) & 1u);   // round-to-nearest-even
    return (unsigned short)(u >> 16);
}

// ---------------- K01f: fused cvt + mode-0 + transpose ----------------------
// blocks [0,512): mode-0+transpose. bid: ig=bid>>6 (i0=ig*5), tile=bid&63
//   (b0=(tile>>3)*32, c0=(tile&7)*32). Thread: 2x2 patch, 5 i accumulators.
// blocks [512,896): f1/f2 -> bf16 convert.
__global__ __launch_bounds__(256) void k01_fused(const float* __restrict__ core,
                                                 const float* __restrict__ f0,
                                                 const float* __restrict__ f1,
                                                 const float* __restrict__ f2,
                                                 unsigned short* __restrict__ A1t,
                                                 unsigned short* __restrict__ f1b,
                                                 unsigned short* __restrict__ f2b) {
    const int bid = blockIdx.x;
    const int tid = threadIdx.x;
    if (bid < 512) {
        __shared__ float f0s[200];                     // f0 rows i0..i0+4
        __shared__ unsigned short tt[32 * 34];         // transposed tile [c][b], pitch 34
        const int i0 = (bid >> 6) * 5;
        const int tile = bid & 63;
        const int b0 = (tile >> 3) * 32;
        const int c0 = (tile & 7) * 32;
        if (tid < 200) f0s[tid] = f0[i0 * A_DIM + tid];
        __syncthreads();

        const int pb = (tid >> 4) * 2;                 // local b of 2x2 patch
        const int pc = (tid & 15) * 2;                 // local c
        float acc[5][4];                               // [ii][{b0c0,b0c1,b1c0,b1c1}]
#pragma unroll
        for (int ii = 0; ii < 5; ++ii)
#pragma unroll
            for (int e = 0; e < 4; ++e) acc[ii][e] = 0.f;

        const float* cp0 = core + (b0 + pb) * 256 + (c0 + pc);
        for (int a = 0; a < A_DIM; ++a) {
            const float* cp = cp0 + a * BC;
            const float2 r0 = *(const float2*)cp;          // [pb  ][pc..pc+1]
            const float2 r1 = *(const float2*)(cp + 256);  // [pb+1][pc..pc+1]
#pragma unroll
            for (int ii = 0; ii < 5; ++ii) {
                const float fa = f0s[ii * A_DIM + a];
                acc[ii][0] += fa * r0.x;   // (b=pb,   c=pc)
                acc[ii][1] += fa * r0.y;   // (b=pb,   c=pc+1)
                acc[ii][2] += fa * r1.x;   // (b=pb+1, c=pc)
                acc[ii][3] += fa * r1.y;   // (b=pb+1, c=pc+1)
            }
        }
        const int rc = tid >> 3;                       // read row (c) 0..31
        const int rb4 = (tid & 7) * 4;                 // read col (b) group of 4
#pragma unroll
        for (int ii = 0; ii < 5; ++ii) {
            if (ii) __syncthreads();
            // store transposed: tt[c][b]; short2 along b (contiguous)
            unsigned short e00 = f2bf(acc[ii][0]);     // c=pc,   b=pb
            unsigned short e10 = f2bf(acc[ii][2]);     // c=pc,   b=pb+1
            unsigned short e01 = f2bf(acc[ii][1]);     // c=pc+1, b=pb
            unsigned short e11 = f2bf(acc[ii][3]);     // c=pc+1, b=pb+1
            *(unsigned int*)&tt[pc * 34 + pb]       = (unsigned int)e00 | ((unsigned int)e10 << 16);
            *(unsigned int*)&tt[(pc + 1) * 34 + pb] = (unsigned int)e01 | ((unsigned int)e11 << 16);
            __syncthreads();
            // coalesced write: row c0+rc, 4 shorts along b
            unsigned short o[4];
#pragma unroll
            for (int u = 0; u < 4; ++u) o[u] = tt[rc * 34 + rb4 + u];
            unsigned int lo = (unsigned int)o[0] | ((unsigned int)o[1] << 16);
            unsigned int hi = (unsigned int)o[2] | ((unsigned int)o[3] << 16);
            *(uint2*)&A1t[(size_t)(i0 + ii) * BC + (c0 + rc) * 256 + b0 + rb4] = make_uint2(lo, hi);
        }
    } else {
        const int idx = (bid - 512) * 256 + tid;       // 49152 float4 per matrix
        const float* src;
        unsigned short* dst;
        int off;
        if (idx < 49152) { src = f1; dst = f1b; off = idx; }
        else             { src = f2; dst = f2b; off = idx - 49152; }
        const float4 v = *(const float4*)&src[off * 4];
        const unsigned int lo = (unsigned int)f2bf(v.x) | ((unsigned int)f2bf(v.y) << 16);
        const unsigned int hi = (unsigned int)f2bf(v.z) | ((unsigned int)f2bf(v.w) << 16);
        *(uint2*)&dst[off * 4] = make_uint2(lo, hi);
    }
}

// ---------------- K2: batched MFMA GEMM, 64x64 tile, BK=32, DMA staging -----
// A = f1b [j][b] (M=768,K=256), B^T = A1t[i] [c][b] (N=256,K=256), C = A2 bf16
// LDS tiles packed [row][32] (64B/row); chunk tid -> row tid>>2, 16B slot tid&3.
__global__ __launch_bounds__(256) void k2_gemm(const unsigned short* __restrict__ f1b,
                                               const unsigned short* __restrict__ A1t,
                                               unsigned short* __restrict__ A2) {
    const int i  = blockIdx.z;
    const int j0 = blockIdx.x * 64;
    const int c0 = blockIdx.y * 64;
    const unsigned short* __restrict__ Bsrc = A1t + i * BC;

    __shared__ unsigned short As[64 * 32];
    __shared__ unsigned short Bs[64 * 32];

    const int tid = threadIdx.x;
    const int lane = tid & 63, wave = tid >> 6;
    const int wm = (wave >> 1) * 32, wn = (wave & 1) * 32;
    const int l16 = lane & 15, q = lane >> 4;

    const int r0 = tid >> 2, o0 = (tid & 3) * 8;     // staging chunk -> (row, 16B slot)
    unsigned short* AsW = &As[wave * 512];           // wave covers chunks wave*64..+63
    unsigned short* BsW = &Bs[wave * 512];

    floatx4 acc[2][2];
#pragma unroll
    for (int p = 0; p < 2; ++p)
#pragma unroll
        for (int r = 0; r < 2; ++r) acc[p][r] = (floatx4)0.f;

    for (int kk = 0; kk < C_DIM; kk += 32) {
        gl2lds16(&f1b[(j0 + r0) * 256 + kk + o0], AsW);
        gl2lds16(&Bsrc[(c0 + r0) * 256 + kk + o0], BsW);
        __syncthreads();
        short8 af[2], bf[2];
#pragma unroll
        for (int p = 0; p < 2; ++p) af[p] = *(const short8*)&As[(wm + p * 16 + l16) * 32 + q * 8];
#pragma unroll
        for (int r = 0; r < 2; ++r) bf[r] = *(const short8*)&Bs[(wn + r * 16 + l16) * 32 + q * 8];
#pragma unroll
        for (int p = 0; p < 2; ++p)
#pragma unroll
            for (int r = 0; r < 2; ++r)
                acc[p][r] = __builtin_amdgcn_mfma_f32_16x16x32_bf16(af[p], bf[r], acc[p][r], 0, 0, 0);
        __syncthreads();
    }
    unsigned short* __restrict__ Cout = A2 + (size_t)i * HID * C_DIM;
#pragma unroll
    for (int p = 0; p < 2; ++p)
#pragma unroll
        for (int r = 0; r < 2; ++r)
#pragma unroll
            for (int rr = 0; rr < 4; ++rr) {
                const int row = j0 + wm + p * 16 + q * 4 + rr;   // C: row=(lane>>4)*4+reg
                const int col = c0 + wn + r * 16 + l16;          //    col=lane&15
                Cout[row * 256 + col] = f2bf(acc[p][r][rr]);
            }
}

// ---------------- K3: gathered MFMA GEMM, 64x64 tile, out f32 ---------------
// A = gathered A2 rows [n][c] (M=8192,K=256), B^T = f2b [k][c] (N=768)
__global__ __launch_bounds__(256) void k3_gemm(const unsigned short* __restrict__ A2,
                                               const unsigned short* __restrict__ f2b,
                                               const int* __restrict__ ids,
                                               float* __restrict__ out) {
    const int n0 = blockIdx.x * 64;
    const int k0 = blockIdx.y * 64;

    __shared__ int ids_s[64];
    __shared__ unsigned short As[64 * 32];
    __shared__ unsigned short Bs[64 * 32];

    const int tid = threadIdx.x;
    if (tid < 64) ids_s[tid] = ids[n0 + tid];
    __syncthreads();

    const int lane = tid & 63, wave = tid >> 6;
    const int wm = (wave >> 1) * 32, wn = (wave & 1) * 32;
    const int l16 = lane & 15, q = lane >> 4;

    const int r0 = tid >> 2, o0 = (tid & 3) * 8;
    const size_t ga = (size_t)ids_s[r0] * 256;       // gathered A row base
    unsigned short* AsW = &As[wave * 512];
    unsigned short* BsW = &Bs[wave * 512];

    floatx4 acc[2][2];
#pragma unroll
    for (int p = 0; p < 2; ++p)
#pragma unroll
        for (int r = 0; r < 2; ++r) acc[p][r] = (floatx4)0.f;

    for (int kk = 0; kk < C_DIM; kk += 32) {
        gl2lds16(&A2[ga + kk + o0], AsW);
        gl2lds16(&f2b[(k0 + r0) * 256 + kk + o0], BsW);
        __syncthreads();
        short8 af[2], bf[2];
#pragma unroll
        for (int p = 0; p < 2; ++p) af[p] = *(const short8*)&As[(wm + p * 16 + l16) * 32 + q * 8];
#pragma unroll
        for (int r = 0; r < 2; ++r) bf[r] = *(const short8*)&Bs[(wn + r * 16 + l16) * 32 + q * 8];
#pragma unroll
        for (int p = 0; p < 2; ++p)
#pragma unroll
            for (int r = 0; r < 2; ++r)
                acc[p][r] = __builtin_amdgcn_mfma_f32_16x16x32_bf16(af[p], bf[r], acc[p][r], 0, 0, 0);
        __syncthreads();
    }
#pragma unroll
    for (int p = 0; p < 2; ++p)
#pragma unroll
        for (int r = 0; r < 2; ++r)
#pragma unroll
            for (int rr = 0; rr < 4; ++rr) {
                const int row = n0 + wm + p * 16 + q * 4 + rr;
                const int col = k0 + wn + r * 16 + l16;
                out[(size_t)row * HID + col] = acc[p][r][rr];
            }
}

extern "C" void kernel_launch(void* const* d_in, const int* in_sizes, int n_in,
                              void* d_out, int out_size, void* d_ws, size_t ws_size,
                              hipStream_t stream) {
    // inputs: 0=x(unused), 1=ids, 2=core, 3=f0, 4=f1, 5=f2
    const int*   ids  = (const int*)d_in[1];
    const float* core = (const float*)d_in[2];
    const float* f0   = (const float*)d_in[3];
    const float* f1   = (const float*)d_in[4];
    const float* f2   = (const float*)d_in[5];
    float* out = (float*)d_out;

    char* ws = (char*)d_ws;
    unsigned short* A1t = (unsigned short*)ws;                 //  5,242,880 B
    unsigned short* A2  = (unsigned short*)(ws + 5242880);     // 15,728,640 B
    unsigned short* f1b = (unsigned short*)(ws + 20971520);    //    393,216 B
    unsigned short* f2b = (unsigned short*)(ws + 21364736);    //    393,216 B

    k01_fused<<<896, 256, 0, stream>>>(core, f0, f1, f2, A1t, f1b, f2b);
    k2_gemm<<<dim3(12, 4, A_DIM), 256, 0, stream>>>(f1b, A1t, A2);
    k3_gemm<<<dim3(128, 12), 256, 0, stream>>>(A2, f2b, ids, out);
}